// Round 10
// baseline (185.209 us; speedup 1.0000x reference)
//
#include <hip/hip_runtime.h>

#define B_ 8
#define S_ 32
#define C_ 3
#define H_ 256
#define W_ 256
#define HW_ (H_*W_)
#define CHW_ (C_*H_*W_)
#define NT_ 24            // K-tiles of 32
#define TILE_ELEMS 8192   // 256 rows x 32 k per pre-split B tile

typedef __attribute__((ext_vector_type(8))) short bf16x8;
typedef __attribute__((ext_vector_type(4))) float f32x4;

// truncation-based hi/lo bf16 split of two floats, packed (x low half, y high)
__device__ __forceinline__ void split2(float x, float y, unsigned &hp, unsigned &lp) {
  unsigned ux = __float_as_uint(x), uy = __float_as_uint(y);
  unsigned hx = ux & 0xFFFF0000u, hy = uy & 0xFFFF0000u;
  float lx = x - __uint_as_float(hx);
  float ly = y - __uint_as_float(hy);
  hp = (ux >> 16) | hy;
  lp = (__float_as_uint(lx) >> 16) | (__float_as_uint(ly) & 0xFFFF0000u);
}

// -------- target row reciprocal norms (one wave per 768-elem row) --------
__global__ void ct_ntg(const float* __restrict__ target, float* __restrict__ rntg) {
  int r = (int)((blockIdx.x * (size_t)blockDim.x + threadIdx.x) >> 6);  // 0..2047
  int lane = threadIdx.x & 63;
  const float* base = target + (size_t)(r >> 8) * CHW_ + (size_t)(r & 255) * W_;
  float ss = 0.f;
#pragma unroll
  for (int c = 0; c < C_; ++c)
#pragma unroll
    for (int tt = 0; tt < W_/64; ++tt) {
      float v = base[c*HW_ + tt*64 + lane];
      ss = fmaf(v, v, ss);
    }
#pragma unroll
  for (int off = 32; off; off >>= 1) ss += __shfl_xor(ss, off);
  if (lane == 0) rntg[r] = 1.0f / fmaxf(sqrtf(ss), 1e-12f);
}

// -------- target -> bf16 hi/lo, per-(b,ktile32) fragment layout --------
__global__ void ct_bsplit(const float* __restrict__ target,
                          ushort* __restrict__ BhG, ushort* __restrict__ BlG) {
  int bx = blockIdx.x;             // b*24 + kt
  int b  = bx / 24, kt = bx % 24;
  int c  = kt >> 3, w0 = (kt & 7) * 32;
  int t  = threadIdx.x;
  int trow = t >> 3, tw = t & 7;   // 8 threads per row, 4 floats each
  const float* base = target + (size_t)(b*C_ + c) * HW_ + w0 + tw*4;
  ushort* oh = BhG + (size_t)bx * TILE_ELEMS;
  ushort* ol = BlG + (size_t)bx * TILE_ELEMS;
#pragma unroll
  for (int i = 0; i < 8; ++i) {
    int row = trow + 32*i;
    float4 v = *(const float4*)(base + (size_t)row * W_);
    unsigned h0, l0, h1, l1;
    split2(v.x, v.y, h0, l0); split2(v.z, v.w, h1, l1);
    int idx = (row>>4)*512 + (tw>>1)*128 + (row&15)*8 + (tw&1)*4;
    *(uint2*)&oh[idx] = make_uint2(h0, h1);
    *(uint2*)&ol[idx] = make_uint2(l0, l1);
  }
}

// -------- fused corr: per-(b,s) 256x256 MFMA GEMM (K=768, bf16 3-term split)
//          + fused A-norms + diagonal reduce + argmax --------
// r2 topology (grid 256, 8 waves, wave tile 128x64, BK=32, 2-barrier loop,
// compiler-scheduled). A: reg-staged to LDS via b128 granule writes.
// B: DIRECT register fragments from pre-split global, even/odd double-buffered,
// issued after barrier2 so they fly under the MFMA phase (r2's overlap pattern).
__global__ __launch_bounds__(512)
void ct_corr_mfma(const float* __restrict__ input,
                  const ushort* __restrict__ BhG, const ushort* __restrict__ BlG,
                  const float* __restrict__ rntg_g,
                  int* __restrict__ shift_out) {
  __shared__ ushort AhL[8192], AlL[8192];     // 32 KB (A only)
  __shared__ float ninSq[256], rnin[256], rntg_s[256], corrS[256];
  __shared__ unsigned long long wkey[4];

  const int bs = blockIdx.x;          // b*S + s
  const int bG = bs >> 5;
  const int t  = threadIdx.x;         // 0..511
  const int lane = t & 63;
  const int wid  = t >> 6;            // 0..7
  const int wm   = wid >> 2;          // 0..1 : M half (128 rows)
  const int wn   = wid & 3;           // 0..3 : N quarter (64 cols)

  const float* Abase = input + (size_t)bs * CHW_;

  if (t < 256) { ninSq[t] = 0.f; corrS[t] = 0.f; rntg_s[t] = rntg_g[bG*256 + t]; }

  f32x4 acc[8][4];
#pragma unroll
  for (int m = 0; m < 8; ++m)
#pragma unroll
    for (int n = 0; n < 4; ++n) acc[m][n] = (f32x4){0.f, 0.f, 0.f, 0.f};

  // thread's two A granules (fixed rows): G0 = t -> row0, G1 = t+512 -> row0+128
  const int row0 = ((t >> 6) & 7) * 16 + (t & 15);   // 0..127
  const int kcol = ((t >> 4) & 3) * 8;               // 0,8,16,24
  float4 pa[4];                                       // 2 granules x 2 float4
  float ssA[2] = {0.f, 0.f};
  bf16x8 bhE[4], blE[4], bhO[4], blO[4];

  auto issueA = [&](int kt) {
    const float* Ab = Abase + (size_t)(kt >> 3) * HW_ + (kt & 7) * 32 + kcol;
    pa[0] = *(const float4*)(Ab + (size_t)row0 * W_);
    pa[1] = *(const float4*)(Ab + (size_t)row0 * W_ + 4);
    pa[2] = *(const float4*)(Ab + (size_t)(row0 + 128) * W_);
    pa[3] = *(const float4*)(Ab + (size_t)(row0 + 128) * W_ + 4);
  };

  auto stashA = [&]() {
#pragma unroll
    for (int g = 0; g < 2; ++g) {
      float4 a = pa[2*g], b = pa[2*g + 1];
      ssA[g] = fmaf(a.x, a.x, fmaf(a.y, a.y, fmaf(a.z, a.z, fmaf(a.w, a.w,
               fmaf(b.x, b.x, fmaf(b.y, b.y, fmaf(b.z, b.z, fmaf(b.w, b.w, ssA[g]))))))));
      uint4 hu, lu;
      split2(a.x, a.y, hu.x, lu.x); split2(a.z, a.w, hu.y, lu.y);
      split2(b.x, b.y, hu.z, lu.z); split2(b.z, b.w, hu.w, lu.w);
      int go = (t + g*512) * 8;                     // granule ushort offset
      *(uint4*)&AhL[go] = hu;
      *(uint4*)&AlL[go] = lu;
    }
  };

#define ISSUE_B(KT, BH, BL) {                                                 \
    const ushort* gh = BhG + (size_t)(bG*NT_ + (KT)) * TILE_ELEMS + wn*2048 + lane*8; \
    const ushort* gl = BlG + (size_t)(bG*NT_ + (KT)) * TILE_ELEMS + wn*2048 + lane*8; \
    _Pragma("unroll")                                                         \
    for (int n = 0; n < 4; ++n) {                                             \
      BH[n] = *(const bf16x8*)(gh + n*512);                                   \
      BL[n] = *(const bf16x8*)(gl + n*512);                                   \
    } }

#define MFMA_BODY(BH, BL) {                                                   \
    _Pragma("unroll")                                                         \
    for (int m = 0; m < 8; ++m) {                                             \
      int rt = wm*8 + m;                                                      \
      bf16x8 ah = *(const bf16x8*)&AhL[rt*512 + lane*8];                      \
      bf16x8 al = *(const bf16x8*)&AlL[rt*512 + lane*8];                      \
      _Pragma("unroll")                                                       \
      for (int n = 0; n < 4; ++n) {                                           \
        acc[m][n] = __builtin_amdgcn_mfma_f32_16x16x32_bf16(ah, BH[n], acc[m][n], 0, 0, 0); \
        acc[m][n] = __builtin_amdgcn_mfma_f32_16x16x32_bf16(ah, BL[n], acc[m][n], 0, 0, 0); \
        acc[m][n] = __builtin_amdgcn_mfma_f32_16x16x32_bf16(al, BH[n], acc[m][n], 0, 0, 0); \
      } } }

  issueA(0);
  ISSUE_B(0, bhE, blE);

  for (int it = 0; it < 12; ++it) {
    const int k0 = 2*it;
    // ---- even tile k0 (uses E, prefetches O) ----
    __syncthreads();                  // A-LDS free (prev MFMA reads done)
    stashA();                         // waits pa(k0)
    __syncthreads();                  // stash visible
    issueA(k0 + 1);
    ISSUE_B(k0 + 1, bhO, blO);        // flies under MFMA below
    MFMA_BODY(bhE, blE);
    // ---- odd tile k0+1 (uses O, prefetches E) ----
    __syncthreads();
    stashA();                         // waits pa(k0+1)
    __syncthreads();
    if (it < 11) {
      issueA(k0 + 2);
      ISSUE_B(k0 + 2, bhE, blE);
    }
    MFMA_BODY(bhO, blO);
  }

  // fused A-norms: thread contributed rows row0 and row0+128 (8 k each per tile)
  atomicAdd(&ninSq[row0], ssA[0]);
  atomicAdd(&ninSq[row0 + 128], ssA[1]);
  __syncthreads();
  if (t < 256) rnin[t] = 1.0f / fmaxf(sqrtf(ninSq[t]), 1e-12f);
  __syncthreads();

  // normalize + reduce upper diagonals (q = col - row >= 0)
#pragma unroll
  for (int n = 0; n < 4; ++n) {
    int col = wn*64 + n*16 + (lane & 15);
    float rc = rntg_s[col];
#pragma unroll
    for (int m = 0; m < 8; ++m) {
      f32x4 a = acc[m][n];
#pragma unroll
      for (int r = 0; r < 4; ++r) {
        int row = wm*128 + m*16 + (lane >> 4)*4 + r;
        int q = col - row;
        if (q >= 0) atomicAdd(&corrS[q], a[r] * rnin[row] * rc);
      }
    }
  }
  __syncthreads();

  // argmax over p (first max = smallest p wins) -> shift = q_best
  if (t < 256) {
    int q = 255 - t;
    float v = corrS[q] / (float)(256 - q);
    unsigned u = __float_as_uint(v);
    u = (u & 0x80000000u) ? ~u : (u | 0x80000000u);
    unsigned long long key = ((unsigned long long)u << 32) | (unsigned)q;
#pragma unroll
    for (int off = 32; off; off >>= 1) {
      unsigned long long o = __shfl_xor(key, off);
      if (o > key) key = o;
    }
    if ((t & 63) == 0) wkey[t >> 6] = key;
  }
  __syncthreads();
  if (t == 0) {
    unsigned long long k = wkey[0];
#pragma unroll
    for (int i = 1; i < 4; ++i) if (wkey[i] > k) k = wkey[i];
    shift_out[bs] = (int)(k & 0xFFFFFFFFull);
  }
}

// -------- shifted gather --------
__global__ void ct_gather(const float* __restrict__ input,
                          const int* __restrict__ shift,
                          float* __restrict__ out) {
  size_t idx = (size_t)blockIdx.x * blockDim.x + threadIdx.x;  // float4 units
  int w4 = (int)(idx & 63);
  int h  = (int)((idx >> 6) & 255);
  int sc = (int)(idx >> 14);
  int bs = sc / 3;
  int hh = h + shift[bs];
  float4 v = make_float4(0.f, 0.f, 0.f, 0.f);
  if (hh < H_) v = *(const float4*)(input + ((size_t)sc << 16) + (size_t)hh * W_ + w4*4);
  *(float4*)(out + (idx << 2)) = v;
}

extern "C" void kernel_launch(void* const* d_in, const int* in_sizes, int n_in,
                              void* d_out, int out_size, void* d_ws, size_t ws_size,
                              hipStream_t stream) {
  const float* input  = (const float*)d_in[0];
  const float* target = (const float*)d_in[1];
  float* out = (float*)d_out;

  float* rntg  = (float*)d_ws;                      // 2048 f
  int*   shift = (int*)(rntg + 2048);               // 256 i
  ushort* BhG  = (ushort*)(shift + 256);            // 8*24*8192 ushort = 3 MB
  ushort* BlG  = BhG + (size_t)B_ * NT_ * TILE_ELEMS;

  ct_ntg       <<<512, 256, 0, stream>>>(target, rntg);
  ct_bsplit    <<<B_ * NT_, 256, 0, stream>>>(target, BhG, BlG);
  ct_corr_mfma <<<B_ * S_, 512, 0, stream>>>(input, BhG, BlG, rntg, shift);
  ct_gather    <<<(B_*S_*C_*H_*W_/4) / 256, 256, 0, stream>>>(input, shift, out);
}